// Round 4
// baseline (349.367 us; speedup 1.0000x reference)
//
#include <hip/hip_runtime.h>
#include <stdint.h>

// SpikingLinearLayer: 20-step LIF over [512 batch, 2048 out] driven by
// binary (10% dense) input spikes x[20,512,2048] through W[2048,2048].
//
// EXACT i8-MFMA path (validated absmax 0.0 in R14-R22): W -> 4 limbs of
// q = round(W*2^31) (3 balanced base-256 digits + top); x in {0,1}.
// C = (sum_j 256^j C_j) * 2^-31, C_j exact int32 i8 GEMMs; int64
// recombine + fp64 scale exact. QUANTIZATION FROZEN (3-limb => O(1)
// spike flips; do not reduce).
//
// Gemm history: R18 128x128 -> 150us @53%; R19 256x128 __syncthreads
// dbuf -> 147us @52% (13.4 TB/s); R20 3-ring counted-vmcnt FAILED
// (171us: sched_barrier pinning + dynamic ring select); R22 2-buffer
// counted-vmcnt clean -> 153.5us @50.6% == NEUTRAL vs R19.
// POST-MORTEM R22: two pipeline schemes == plain __syncthreads, and
// byte cuts at constant read/mfma gain ~nothing => NOT latency-bound,
// NOT delivery-byte-bound. Accounting: per CU per kc, MFMA=1171cy
// (53%==MfmaUtil), LDS traffic 176KB/2205cy = 80 B/cy/CU == the
// ds_read_b128 practical port ceiling (~85). ==> LDS-PORT-BOUND.
//
// R23: cut LDS bytes/mfma via register blocking. Wave tile 64x64->
// 64x128 (2x4 accs): 0.75 KB read/mfma (-25%); block 256x256 (staged
// 1.97->1.34 GB, -32%). 8 accs = 128 acc regs -> ~200 unified ->
// launch_bounds(512,2), 1 block/CU (LDS 64KB). Per CU/kc: LDS 128KB
// (was 176), MFMA 1171cy, delivery 32KB -- balanced. Counted-vmcnt
// KSTEP kept (1 blk/CU has no partner block to hide drains).

#define STEPS  20
#define BATCH  512
#define DIM    2048

// ---- ws layout (MFMA path)
#define XQ_OFF   0ULL
#define WQ_OFF   20971520ULL          // xq: 80*32*8192
#define C_OFF    37748736ULL          // + wq: 4*16*32*8192

#define GLOBAL_AS __attribute__((address_space(1)))
#define LDS_AS    __attribute__((address_space(3)))

typedef int v4i  __attribute__((ext_vector_type(4)));
typedef int v16i __attribute__((ext_vector_type(16)));

// ============================ MFMA path ============================

// xq[mt<80][kc<32][w<4][mm<128][16] : byte = (x[m][k]!=0)
//   m = mt*128+mm, k = kc*64 + w*16 + j   (m = t*512+b natural order)
__global__ __launch_bounds__(256)
void prep_x_kernel(const float* __restrict__ x, char* __restrict__ wsb)
{
    const int bid = blockIdx.x;           // bid = mt*32 + kc
    const int kc = bid & 31, mt = bid >> 5;
    const int tid = threadIdx.x;
    char* outb = wsb + (size_t)bid * 8192;
#pragma unroll
    for (int it = 0; it < 8; ++it) {
        const int idx = it * 256 + tid;
        const int mm = idx >> 4;
        const int kk4 = (idx & 15) << 2;
        const float4 v = *reinterpret_cast<const float4*>(
            x + (size_t)(mt * 128 + mm) * DIM + kc * 64 + kk4);
        uchar4 o;
        o.x = (v.x != 0.0f); o.y = (v.y != 0.0f);
        o.z = (v.z != 0.0f); o.w = (v.w != 0.0f);
        *reinterpret_cast<uchar4*>(
            outb + (((kk4 >> 4) * 128 + mm) << 4) + (kk4 & 15)) = o;
    }
}

// wq[limb<4][nt<16][kc<32][w<4][nn<128][16] :
//   byte = digit_limb(round(W[o][k]*2^31)), o = nt*128+nn, k = kc*64+w*16+j
// digits staged in LDS, planes written out linearly (coalesced).
__global__ __launch_bounds__(256)
void prep_w_kernel(const float* __restrict__ W, char* __restrict__ wsb)
{
    __shared__ __align__(16) char pl[4][8192];
    const int bid = blockIdx.x;           // bid = nt*32 + kc
    const int kc = bid & 31, nt = bid >> 5;
    const int tid = threadIdx.x;
    char* wqb = wsb + WQ_OFF;
#pragma unroll
    for (int it = 0; it < 8; ++it) {
        const int idx = it * 256 + tid;
        const int nn = idx >> 4;
        const int kk4 = (idx & 15) << 2;
        const float4 v = *reinterpret_cast<const float4*>(
            W + (size_t)(nt * 128 + nn) * DIM + kc * 64 + kk4);
        int dg[4][4];
        const float* vp = &v.x;
#pragma unroll
        for (int c = 0; c < 4; ++c) {
            long long q = __double2ll_rn((double)vp[c] * 2147483648.0);
#pragma unroll
            for (int j = 0; j < 3; ++j) {
                int d = (int)(q & 255);
                if (d >= 128) d -= 256;        // balanced digit
                dg[c][j] = d;
                q = (q - d) >> 8;
            }
            dg[c][3] = (int)q;                 // |.| <= ~97 for |W| < 0.76
        }
        const int sub = (((kk4 >> 4) * 128 + nn) << 4) + (kk4 & 15);
#pragma unroll
        for (int j = 0; j < 4; ++j) {
            uchar4 o;
            o.x = (unsigned char)(dg[0][j] & 255);
            o.y = (unsigned char)(dg[1][j] & 255);
            o.z = (unsigned char)(dg[2][j] & 255);
            o.w = (unsigned char)(dg[3][j] & 255);
            *reinterpret_cast<uchar4*>(&pl[j][sub]) = o;
        }
    }
    __syncthreads();
#pragma unroll
    for (int j = 0; j < 4; ++j) {
        char* dst = wqb + ((size_t)((j * 16 + nt) * 32 + kc)) * 8192;
#pragma unroll
        for (int rep = 0; rep < 2; ++rep) {
            const int off = (rep * 256 + tid) * 16;
            *reinterpret_cast<int4*>(dst + off) =
                *reinterpret_cast<const int4*>(&pl[j][off]);
        }
    }
}

// C_j[m][o_local] int16 planes. R23: 256x256 per limb, 512 thr /
// 8 waves (wy = w&3 -> m-sub of 64, wx = w>>2 -> n-sub of 128), each
// wave 2x4 of 32x32x32 i8 mfma (8 accs: 0.75 KB LDS-read per mfma).
// A = two stacked xq planes (16 KB) + B = two wq planes (16 KB) per kc.
// 2-buffer counted-vmcnt pipeline (R22 KSTEP, vmcnt(4): one stage = 4
// loads). Grid: limb slow, ntc mid, mtb FAST (B sharers consecutive;
// xq LLC-resident). 1 block/CU (regs): launch_bounds(512,2).
__global__ __launch_bounds__(512, 2)
void gemm_i8_kernel(const char* __restrict__ wsb_c, short* __restrict__ cp,
                    int nt0, int ntc_cnt, int no)
{
    __shared__ __align__(16) char lds[2][32768]; // [buf][A0 8K|A1 8K|B0 8K|B1 8K]

    const int bid = blockIdx.x;           // mtb fastest, ntc mid, limb slow
    const int mtb = bid % 40;
    const int rest = bid / 40;
    const int ntc = rest % ntc_cnt;
    const int limb = rest / ntc_cnt;

    const int tid = threadIdx.x;
    const int lane = tid & 63, w = tid >> 6;   // 8 waves
    const int kh = lane >> 5, ln = lane & 31;
    const int wy = w & 3, wx = w >> 2;         // wy<4: m-64; wx<2: n-128

    const char* abase0 = wsb_c + XQ_OFF + ((size_t)(2 * mtb) * 32) * 8192;
    const char* abase1 = abase0 + (size_t)32 * 8192;
    const int ntA = limb * 16 + nt0 + 2 * ntc; // first of two wq planes
    const char* bbase0 = wsb_c + WQ_OFF + ((size_t)(ntA * 32)) * 8192;
    const char* bbase1 = wsb_c + WQ_OFF + ((size_t)((ntA + 1) * 32)) * 8192;

    // A read: plane (wy>>1), 64-row block (wy&1); a1 = +32 rows (+512B)
    const int atile = (wy >> 1) * 8192;
    const int aoffl = ((kh * 128) + (wy & 1) * 64 + ln) << 4;
    // B read: plane wx; b_n = cols n*32+ln  (+n*512B)
    const int btile = 16384 + wx * 8192;
    const int boffl = ((kh * 128) + ln) << 4;
    const int stg = w * 1024 + (lane << 4);    // wave's 1 KB DMA slot

    v16i acc[2][4];
#pragma unroll
    for (int m = 0; m < 2; ++m)
#pragma unroll
        for (int n = 0; n < 4; ++n)
#pragma unroll
            for (int r = 0; r < 16; ++r) acc[m][n][r] = 0;

    LDS_AS char* const lb0 = (LDS_AS char*)(&lds[0][0]);
    LDS_AS char* const lb1 = (LDS_AS char*)(&lds[1][0]);

    // stage kc-chunk kcv into buffer dstp (4 loads / wave)
#define STAGE(dstp, kcv) do {                                               \
        const size_t src_ = (size_t)(kcv) * 8192 + stg;                     \
        __builtin_amdgcn_global_load_lds(                                   \
            (const GLOBAL_AS void*)(abase0 + src_),                         \
            (LDS_AS void*)((dstp) + w * 1024), 16, 0, 0);                   \
        __builtin_amdgcn_global_load_lds(                                   \
            (const GLOBAL_AS void*)(abase1 + src_),                         \
            (LDS_AS void*)((dstp) + 8192 + w * 1024), 16, 0, 0);            \
        __builtin_amdgcn_global_load_lds(                                   \
            (const GLOBAL_AS void*)(bbase0 + src_),                         \
            (LDS_AS void*)((dstp) + 16384 + w * 1024), 16, 0, 0);           \
        __builtin_amdgcn_global_load_lds(                                   \
            (const GLOBAL_AS void*)(bbase1 + src_),                         \
            (LDS_AS void*)((dstp) + 24576 + w * 1024), 16, 0, 0);           \
    } while (0)

    // One kc step; CUR compile-time 0/1 (loop unrolled x2).
    // vmcnt(4) retires stage(kcv) (4 oldest); stage(kcv+1) in flight.
    // s=0 reads + 8 mfma; s=1 reads; lgkmcnt(0)+barrier licenses the
    // overwrite of buf[CUR] (kcv+2 maps to the same buffer); STAGE;
    // 8 mfma (s=1).
#define KSTEP(kcv, CUR) do {                                                 \
        if ((kcv) == 31) {                                                   \
            asm volatile("s_waitcnt vmcnt(0) lgkmcnt(0)" ::: "memory");      \
        } else {                                                             \
            asm volatile("s_waitcnt vmcnt(4) lgkmcnt(0)" ::: "memory");      \
        }                                                                    \
        __builtin_amdgcn_s_barrier();                                        \
        asm volatile("" ::: "memory");                                       \
        const char* A_ = (const char*)(&lds[(CUR)][0]) + atile;              \
        const char* B_ = (const char*)(&lds[(CUR)][0]) + btile;              \
        v4i a0_[2], b0_[4];                                                  \
        a0_[0] = *reinterpret_cast<const v4i*>(A_ + aoffl);                  \
        a0_[1] = *reinterpret_cast<const v4i*>(A_ + aoffl + 512);            \
        _Pragma("unroll")                                                    \
        for (int n = 0; n < 4; ++n)                                          \
            b0_[n] = *reinterpret_cast<const v4i*>(B_ + boffl + n * 512);    \
        _Pragma("unroll")                                                    \
        for (int m = 0; m < 2; ++m)                                          \
            _Pragma("unroll")                                                \
            for (int n = 0; n < 4; ++n)                                      \
                acc[m][n] = __builtin_amdgcn_mfma_i32_32x32x32_i8(           \
                    a0_[m], b0_[n], acc[m][n], 0, 0, 0);                     \
        v4i a1_[2], b1_[4];                                                  \
        a1_[0] = *reinterpret_cast<const v4i*>(A_ + aoffl + 4096);           \
        a1_[1] = *reinterpret_cast<const v4i*>(A_ + aoffl + 4608);           \
        _Pragma("unroll")                                                    \
        for (int n = 0; n < 4; ++n)                                          \
            b1_[n] = *reinterpret_cast<const v4i*>(B_ + boffl + 4096 + n * 512);\
        asm volatile("s_waitcnt lgkmcnt(0)" ::: "memory");                   \
        __builtin_amdgcn_s_barrier();                                        \
        asm volatile("" ::: "memory");                                       \
        if ((kcv) + 2 < 32) STAGE((CUR) ? lb1 : lb0, (kcv) + 2);             \
        _Pragma("unroll")                                                    \
        for (int m = 0; m < 2; ++m)                                          \
            _Pragma("unroll")                                                \
            for (int n = 0; n < 4; ++n)                                      \
                acc[m][n] = __builtin_amdgcn_mfma_i32_32x32x32_i8(           \
                    a1_[m], b1_[n], acc[m][n], 0, 0, 0);                     \
    } while (0)

    // prologue: kc=0 -> buf0, kc=1 -> buf1 (8 loads in flight / wave)
    STAGE(lb0, 0);
    STAGE(lb1, 1);

    for (int kc = 0; kc < 32; kc += 2) {
        KSTEP(kc, 0);
        KSTEP(kc + 1, 1);
    }
#undef KSTEP
#undef STAGE

    // epilogue: C/D layout col=lane&31, row=(r&3)+8*(r>>2)+4*(lane>>5)
    short* cpl = cp + (size_t)limb * 10240 * no;
    const int m_base = mtb * 256 + wy * 64;
    const int o_base = ntc * 256 + wx * 128 + ln;
#pragma unroll
    for (int m = 0; m < 2; ++m) {
#pragma unroll
        for (int r = 0; r < 16; ++r) {
            const int row = (r & 3) + ((r >> 2) << 3) + (kh << 2);
            const size_t mr = (size_t)(m_base + m * 32 + row) * no;
#pragma unroll
            for (int n = 0; n < 4; ++n)
                cpl[mr + o_base + n * 32] = (short)acc[m][n][r];
        }
    }
}

// LIF scan: exact int64 recombine of 4 int16 limb planes, fp64 scale
// by 2^-31 (exact), reference op order.
__global__ __launch_bounds__(256)
void lif_kernel(const short* __restrict__ cp, float* __restrict__ out,
                int o0, int no, int shift)
{
    const int g = blockIdx.x * 256 + threadIdx.x;
    const int b = g >> shift;                  // shift = log2(no/4)
    const int oq = g & ((1 << shift) - 1);
    const int o_local = oq << 2;
    const size_t plane = (size_t)10240 * no;

    const double A_M = 1.0 - 1.0 / 20.0;   // 0.95
    const double DTM = 1.0 / 20.0;         // 0.05
    const double A_S = 1.0 - 1.0 / 5.0;    // 0.8
    double V[4], I[4];
#pragma unroll
    for (int u = 0; u < 4; ++u) { V[u] = 0.0; I[u] = 0.0; }

#pragma unroll
    for (int t = 0; t < STEPS; ++t) {
        const size_t ix = (size_t)(t * BATCH + b) * no + o_local;
        const short4 c0 = *reinterpret_cast<const short4*>(cp + ix);
        const short4 c1 = *reinterpret_cast<const short4*>(cp + plane + ix);
        const short4 c2 = *reinterpret_cast<const short4*>(cp + 2 * plane + ix);
        const short4 c3 = *reinterpret_cast<const short4*>(cp + 3 * plane + ix);
        const short* p0 = &c0.x; const short* p1 = &c1.x;
        const short* p2 = &c2.x; const short* p3 = &c3.x;
        float4 s;
        float* sp = &s.x;
#pragma unroll
        for (int u = 0; u < 4; ++u) {
            const long long tot = (long long)p0[u]
                + ((long long)p1[u] << 8)
                + ((long long)p2[u] << 16)
                + ((long long)p3[u] << 24);
            const double val = (double)tot * 4.6566128730773926e-10; // 2^-31
            V[u] = A_M * V[u] + DTM * I[u];
            float sv = 0.0f;
            if (V[u] >= 1.0) { sv = 1.0f; V[u] = 0.0; }
            sp[u] = sv;
            I[u] = A_S * I[u] + val;
        }
        *reinterpret_cast<float4*>(
            out + (size_t)(t * BATCH + b) * DIM + o0 + o_local) = s;
    }
}

// ===================== fallback (R10 sparse path) =====================

#define B_TILE 2
#define O_TILE 256
#define NT     512
#define KT     32
#define NSLAB  (DIM / KT)
#define ROWB   1024

__global__ __launch_bounds__(256)
void transpose_kernel(const float* __restrict__ W, float* __restrict__ WT)
{
    __shared__ float tile[64][65];
    const int tid = threadIdx.x;
    const int c4 = (tid & 15) * 4;
    const int rr = tid >> 4;
    const int k0 = blockIdx.x * 64, o0 = blockIdx.y * 64;
#pragma unroll
    for (int i = 0; i < 64; i += 16) {
        const float4 v = *reinterpret_cast<const float4*>(
            W + (size_t)(o0 + rr + i) * DIM + k0 + c4);
        tile[c4 + 0][rr + i] = v.x;
        tile[c4 + 1][rr + i] = v.y;
        tile[c4 + 2][rr + i] = v.z;
        tile[c4 + 3][rr + i] = v.w;
    }
    __syncthreads();
#pragma unroll
    for (int i = 0; i < 64; i += 16) {
        float4 v;
        v.x = tile[rr + i][c4 + 0];
        v.y = tile[rr + i][c4 + 1];
        v.z = tile[rr + i][c4 + 2];
        v.w = tile[rr + i][c4 + 3];
        *reinterpret_cast<float4*>(
            WT + (size_t)(k0 + rr + i) * DIM + o0 + c4) = v;
    }
}

__global__ __launch_bounds__(NT, 6)
void snn_lif_kernel(const float* __restrict__ x,
                    const float* __restrict__ WT,
                    float* __restrict__ out)
{
    __shared__ __align__(16) float wlds[(KT * ROWB) / 4];

    const int tid  = threadIdx.x;
    const int lane = tid & 63;
    const int w    = tid >> 6;
    const int bl   = w & 1;
    const int tq   = w >> 1;
    const int o_blk = blockIdx.x & 7;
    const int b_blk = blockIdx.x >> 3;
    const int b  = b_blk * B_TILE + bl;
    const int o0 = o_blk * O_TILE;

    double acc[5][4];
#pragma unroll
    for (int tt = 0; tt < 5; ++tt)
#pragma unroll
        for (int u = 0; u < 4; ++u) acc[tt][u] = 0.0;

    const int kl = lane & 31;
    float xr[5];
#pragma unroll
    for (int m = 0; m < 5; ++m)
        xr[m] = x[((size_t)(tq * 5 + m) * BATCH + b) * DIM + kl];

    const char*   gb   = (const char*)wlds + (lane << 4);
    LDS_AS char*  ldsb = (LDS_AS char*)wlds;
    const float*  wsrc = WT + o0 + (lane << 2);

    for (int kt = 0; kt < NSLAB; ++kt) {
        const int k0 = kt * KT;
        __syncthreads();
#pragma unroll
        for (int it = 0; it < 4; ++it) {
            const int r = w + it * 8;
            __builtin_amdgcn_global_load_lds(
                (const GLOBAL_AS void*)(wsrc + (size_t)(k0 + r) * DIM),
                (LDS_AS void*)(ldsb + r * ROWB), 16, 0, 0);
        }
        unsigned mk[5];
#pragma unroll
        for (int m = 0; m < 5; ++m)
            mk[m] = (unsigned)__ballot(xr[m] != 0.0f);
        __syncthreads();
        if (kt + 1 < NSLAB) {
            const int k1 = k0 + KT;
#pragma unroll
            for (int m = 0; m < 5; ++m)
                xr[m] = x[((size_t)(tq * 5 + m) * BATCH + b) * DIM + k1 + kl];
        }
#pragma unroll
        for (int m = 0; m < 5; ++m) {
            unsigned msk = mk[m];
            while (msk & (msk - 1)) {
                const int r0 = __builtin_ctz(msk); msk &= msk - 1;
                const int r1 = __builtin_ctz(msk); msk &= msk - 1;
                const float4 va = *reinterpret_cast<const float4*>(gb + (r0 << 10));
                const float4 vb = *reinterpret_cast<const float4*>(gb + (r1 << 10));
                acc[m][0] += (double)va.x; acc[m][1] += (double)va.y;
                acc[m][2] += (double)va.z; acc[m][3] += (double)va.w;
                acc[m][0] += (double)vb.x; acc[m][1] += (double)vb.y;
                acc[m][2] += (double)vb.z; acc[m][3] += (double)vb.w;
            }
            if (msk) {
                const int r = __builtin_ctz(msk);
                const float4 wv = *reinterpret_cast<const float4*>(gb + (r << 10));
                acc[m][0] += (double)wv.x; acc[m][1] += (double)wv.y;
                acc[m][2] += (double)wv.z; acc[m][3] += (double)wv.w;
            }
        }
    }

    const double A_M = 1.0 - 1.0 / 20.0;
    const double DTM = 1.0 / 20.0;
    const double A_S = 1.0 - 1.0 / 5.0;

    __syncthreads();
    double2* hand = reinterpret_cast<double2*>(wlds);
    const int hbase = bl * 256 + (lane << 2);
    const size_t obase = (size_t)o0 + (lane << 2);

    for (int seg = 0; seg < 4; ++seg) {
        if (tq == seg) {
            double V[4], I[4];
            if (seg == 0) {
#pragma unroll
                for (int u = 0; u < 4; ++u) { V[u] = 0.0; I[u] = 0.0; }
            } else {
#pragma unroll
                for (int u = 0; u < 4; ++u) {
                    const double2 h = hand[hbase + u];
                    V[u] = h.x; I[u] = h.y;
                }
            }
#pragma unroll
            for (int tt = 0; tt < 5; ++tt) {
                const int t = seg * 5 + tt;
                float4 s;
                float* sp = &s.x;
#pragma unroll
                for (int u = 0; u < 4; ++u) {
                    V[u] = A_M * V[u] + DTM * I[u];
                    float sv = 0.0f;
                    if (V[u] >= 1.0) { sv = 1.0f; V[u] = 0.0; }
                    sp[u] = sv;
                    I[u] = A_S * I[u] + acc[tt][u];
                }
                *reinterpret_cast<float4*>(
                    out + ((size_t)t * BATCH + b) * DIM + obase) = s;
            }
            if (seg < 3) {
#pragma unroll
                for (int u = 0; u < 4; ++u)
                    hand[hbase + u] = make_double2(V[u], I[u]);
            }
        }
        __syncthreads();
    }
}

// ============================== host ==============================

extern "C" void kernel_launch(void* const* d_in, const int* in_sizes, int n_in,
                              void* d_out, int out_size, void* d_ws, size_t ws_size,
                              hipStream_t stream) {
    const float* x = (const float*)d_in[0];   // [20, 512, 2048] spikes
    const float* W = (const float*)d_in[1];   // [2048, 2048]
    float* out = (float*)d_out;               // [20, 512, 2048]
    char* wsb = (char*)d_ws;

    // choose the largest o-chunk whose int16 C planes fit in ws
    // need(no) = C_OFF + 4 * 10240 * no * 2 bytes
    // R23 gemm needs 256-wide n-chunks => no >= 256.
    int no = 0, shift = 0;
    if      (ws_size >= C_OFF + 81920ULL * 2048) { no = 2048; shift = 9; }
    else if (ws_size >= C_OFF + 81920ULL * 1024) { no = 1024; shift = 8; }
    else if (ws_size >= C_OFF + 81920ULL * 512)  { no = 512;  shift = 7; }
    else if (ws_size >= C_OFF + 81920ULL * 256)  { no = 256;  shift = 6; }

    if (no >= 256) {
        // exact i8-MFMA path (R23 256x256 2x4-blocked; single-shot at no=2048)
        prep_x_kernel<<<2560, 256, 0, stream>>>(x, wsb);
        prep_w_kernel<<<512, 256, 0, stream>>>(W, wsb);
        short* cp = (short*)(wsb + C_OFF);
        const int ntc_cnt = no / 256;
        for (int nt0 = 0; nt0 < 16; nt0 += 2 * ntc_cnt) {
            gemm_i8_kernel<<<40 * ntc_cnt * 4, 512, 0, stream>>>(
                (const char*)wsb, cp, nt0, ntc_cnt, no);
            lif_kernel<<<no / 2, 256, 0, stream>>>(
                (const short*)cp, out, nt0 * 128, no, shift);
        }
    } else {
        // fallback: R10 sparse-gather pipeline (known-good, 580 us)
        float* WT = (float*)d_ws;
        dim3 tb(256);
        dim3 tg(DIM / 64, DIM / 64);
        transpose_kernel<<<tg, tb, 0, stream>>>(W, WT);
        const int grid = (BATCH / B_TILE) * (DIM / O_TILE);
        snn_lif_kernel<<<grid, NT, 0, stream>>>(x, WT, out);
    }
}